// Round 4
// baseline (123.131 us; speedup 1.0000x reference)
//
#include <hip/hip_runtime.h>

// Vanilla RNN B=4096 S=512 I=1 H=16 O=1 — serial-chain latency optimization.
//
// R16 = R15 with the two weight-split MFMAs made INDEPENDENT.
// R15 post-mortem: 255 cyc/step = 2 serial MFMA dep-latencies (~55 each;
// a_hi accumulated into a_lo's C -> latencies ADD) + 4-row trans tail ~95
// + init/hazards. The serialization was self-inflicted: both MFMAs read
// the same gB and couple only through C. Now:
//   c_hi = mfma(a_hi, gB, c_init);  c_lo = mfma(a_lo, gB, 0);  c = c_hi+c_lo
// Path loses one MFMA latency (~50 cyc), gains 4 v_add_f32 (~6 on path).
// Everything else (fragment layout, g-trick, tail, loads, epilogue) is
// verbatim R15 — that structure is HW-verified (passed, absmax 1.95e-3).
//
// Fragment alignment (zero cross-lane ops in the step): for 16x16x16_f16,
// C/D: col=lane&15, row=4*(lane>>4)+reg; B: col=lane&15, k=4*(lane>>4)+reg
// — SAME map. D reg r converts lane-locally to B elem k for the next step.
// col = batch (16 batches/wave, 256 waves), row/k = h-index.
//
// g-trick: state g = 1/(2^s+1), h = 1-2g;
// s = S2LE*(rowsum(W_hh)+b_ih+b_hh) + S2LE*W_ih*x_t + (-2*S2LE*W_hh)·g.
// A = -2*S2LE*W_hh split f16 hi+lo (weight quant error ~2^-22); remaining
// error is per-step f16 RNE quantization of g (~2.4e-4, contracted).
//
// Loads: R6 staged float4 blocks, modulo-2 named buffers, no per-iter
// vmcnt drain. Epilogue off the hot loop: in-lane 4-row partial then
// shfl_xor 16/32.

#define S2LE 2.8853900817779268f  // 2*log2(e)

typedef float    float4_ __attribute__((ext_vector_type(4)));
typedef _Float16 half4_  __attribute__((ext_vector_type(4)));

#if defined(__has_builtin)
#if __has_builtin(__builtin_amdgcn_mfma_f32_16x16x16f16)
#define HAVE_MFMA_BUILTIN 1
#endif
#endif

#ifdef HAVE_MFMA_BUILTIN
#define MFMA16(A, B, C) __builtin_amdgcn_mfma_f32_16x16x16f16((A), (B), (C), 0, 0, 0)
#else
static __device__ __forceinline__ float4_ mfma16_asm(half4_ a, half4_ b, float4_ c) {
    // Fallback. s_nop 1 before: VALU-write -> MFMA src read (2 wait states).
    // s_nop 7 after: 4-pass MFMA dst -> VALU read (~6 wait states; 8 covers).
    asm volatile("s_nop 1\n\t"
                 "v_mfma_f32_16x16x16_f16 %0, %1, %2, %0\n\t"
                 "s_nop 7"
                 : "+v"(c) : "v"(a), "v"(b));
    return c;
}
#define MFMA16(A, B, C) mfma16_asm((A), (B), (C))
#endif

__global__ __launch_bounds__(64) void rnn_kernel(
    const float* __restrict__ x,
    const float* __restrict__ W_ih,
    const float* __restrict__ W_hh,
    const float* __restrict__ b_ih,
    const float* __restrict__ b_hh,
    const float* __restrict__ W_fc,
    const float* __restrict__ b_fc,
    float* __restrict__ out)
{
    const int l   = (int)threadIdx.x;  // 0..63
    const int col = l & 15;            // batch-in-group; A-row i; B/C/D col
    const int qr  = l >> 4;            // 0..3
    const int i4  = qr * 4;            // A k-base; C/D row-base
    const int b   = (int)(blockIdx.x * 16u + (unsigned)col);

    const float wsc = -2.0f * S2LE;

    // A-frag: A[i][k], i = col (lane&15), k = i4+r. Split f16 hi+lo.
    half4_ a_hi, a_lo;
#pragma unroll
    for (int r = 0; r < 4; ++r) {
        float u = wsc * W_hh[col * 16 + i4 + r];
        _Float16 hi = (_Float16)u;
        a_hi[r] = hi;
        a_lo[r] = (_Float16)(u - (float)hi);
    }

    // C-init constants for this lane's 4 output rows (i4+r).
    float wihS[4], biasS[4], wfcr[4];
#pragma unroll
    for (int r = 0; r < 4; ++r) {
        const int ri = i4 + r;
        float rs = 0.0f;
#pragma unroll
        for (int k = 0; k < 16; ++k) rs += W_hh[ri * 16 + k];
        wihS[r]  = W_ih[ri] * S2LE;
        biasS[r] = (rs + b_ih[ri] + b_hh[ri]) * S2LE;
        wfcr[r]  = W_fc[ri];
    }
    float cfc = b_fc[0];
#pragma unroll
    for (int k = 0; k < 16; ++k) cfc += W_fc[k];

    const float4_* __restrict__ xv = (const float4_*)(x + (size_t)b * 512);

    const float4_ zero4 = {0.0f, 0.0f, 0.0f, 0.0f};

    half4_ gB = {(_Float16)0.5f, (_Float16)0.5f, (_Float16)0.5f, (_Float16)0.5f};
    float4_ gf = {0.5f, 0.5f, 0.5f, 0.5f};  // last f32 g, for epilogue

    // One step: 4 lane-local C-init fmas (x_t f32, off-path), 2 INDEPENDENT
    // MFMAs (latencies overlap), 4-add merge, lane-local exp2-sigmoid tail,
    // f16 RNE repack. Tail verbatim R15.
#define STEP(XT) do { \
    float xt_ = (XT); \
    float4_ ci; \
    ci[0] = fmaf(xt_, wihS[0], biasS[0]); \
    ci[1] = fmaf(xt_, wihS[1], biasS[1]); \
    ci[2] = fmaf(xt_, wihS[2], biasS[2]); \
    ci[3] = fmaf(xt_, wihS[3], biasS[3]); \
    float4_ ch = MFMA16(a_hi, gB, ci); \
    float4_ cl = MFMA16(a_lo, gB, zero4); \
    float4_ c = ch + cl; \
    gf[0] = __builtin_amdgcn_rcpf(__builtin_amdgcn_exp2f(c[0]) + 1.0f); \
    gf[1] = __builtin_amdgcn_rcpf(__builtin_amdgcn_exp2f(c[1]) + 1.0f); \
    gf[2] = __builtin_amdgcn_rcpf(__builtin_amdgcn_exp2f(c[2]) + 1.0f); \
    gf[3] = __builtin_amdgcn_rcpf(__builtin_amdgcn_exp2f(c[3]) + 1.0f); \
    gB[0] = (_Float16)gf[0]; \
    gB[1] = (_Float16)gf[1]; \
    gB[2] = (_Float16)gf[2]; \
    gB[3] = (_Float16)gf[3]; \
} while (0)

// 16 recurrent steps from a 4-x-float4 staged block.
#define BLOCK(BUF) do { \
    _Pragma("unroll") \
    for (int j = 0; j < 4; ++j) { \
        STEP((BUF)[j][0]); \
        STEP((BUF)[j][1]); \
        STEP((BUF)[j][2]); \
        STEP((BUF)[j][3]); \
    } \
} while (0)

    float4_ bufA[4], bufB[4];
#pragma unroll
    for (int j = 0; j < 4; ++j) bufA[j] = xv[j];  // block 0

    // Unroll-2 modulo pipeline over 32 blocks of 16 timesteps (R6): loads
    // issue one full block ahead; no register rotation, no per-iter drain.
#pragma unroll 1
    for (int i = 0; i < 32; i += 2) {
#pragma unroll
        for (int j = 0; j < 4; ++j) bufB[j] = xv[(4 * (i + 1) + j) & 127];
        BLOCK(bufA);
#pragma unroll
        for (int j = 0; j < 4; ++j) bufA[j] = xv[(4 * (i + 2) + j) & 127];
        BLOCK(bufB);
    }
#undef BLOCK
#undef STEP

    // out[b] = cfc - 2 * sum_i wfc_i * g_i  (h = 1-2g). Lane partial over
    // its 4 rows (f32 g), then cross-lane sum over the 4 qr groups.
    float p = gf[0] * wfcr[0] + gf[1] * wfcr[1] + gf[2] * wfcr[2] + gf[3] * wfcr[3];
    p += __shfl_xor(p, 16, 64);
    p += __shfl_xor(p, 32, 64);
    if (qr == 0) out[b] = fmaf(-2.0f, p, cfc);
}

extern "C" void kernel_launch(void* const* d_in, const int* in_sizes, int n_in,
                              void* d_out, int out_size, void* d_ws, size_t ws_size,
                              hipStream_t stream) {
    const float* x    = (const float*)d_in[0];
    const float* W_ih = (const float*)d_in[1];
    const float* W_hh = (const float*)d_in[2];
    const float* b_ih = (const float*)d_in[3];
    const float* b_hh = (const float*)d_in[4];
    const float* W_fc = (const float*)d_in[5];
    const float* b_fc = (const float*)d_in[6];
    float* out = (float*)d_out;

    rnn_kernel<<<256, 64, 0, stream>>>(x, W_ih, W_hh, b_ih, b_hh, W_fc, b_fc, out);
}

// Round 5
// 91.460 us; speedup vs baseline: 1.3463x; 1.3463x over previous
//
#include <hip/hip_runtime.h>

// Vanilla RNN B=4096 S=512 I=1 H=16 O=1 — serial-chain latency optimization.
// Lane = (batch, h-row); 16 lanes/batch; 1024 waves = 1 wave/SIMD, one
// serial chain per SIMD. Wall = 512 * (F + T) per chain, independent of
// wave packing (R11 measured: 2 chains/wave at half the waves = exactly
// 2x wall). F = front issue span ~75-85 cyc, T = tree+exp+rcp ~90 cyc.
//
// R17 = exact revert to the R12 champion (best measured: 91.8 us headline,
// ~40.6-41.3 us kernel, absmax 1.22e-4). Post-R16 ledger, in cyc/step vs
// this kernel's 192: R13 split-exp +0, R14 split-dot +22, R15 MFMA +63,
// R16 MFMA-indep +100. All structural alternatives measured WORSE; all
// micro-edits measured zero. This structure is the measured local optimum
// on every tested axis: chain topology (R12: 2x8 beats 4x4 by 2 instrs),
// tail algebra (R5 poly +93, R8 newton +17, R13 split-exp +0), lane
// decomposition (R11 packing = exact 2x, R14 split-dot worse), matrix
// cores (R15/R16 worse — MFMA issue+dep latency at 1 wave/SIMD plus f16
// repack exceeds the DPP front it replaces).
//
// Why this is the floor: the recurrence admits no cross-step parallelism;
// B=4096 at 16 lanes/batch exactly fills 1024 SIMDs with 1 chain each.
// VALUBusy 42% / HBM 1.3% / occupancy 9% — latency-bound by construction;
// the unused 58% of issue slots cannot be filled by more waves (R14) nor
// by fewer instructions (R15/R16) without adding more latency than saved.
//
// Head hazard discipline (R8/R9 corruption class — NEVER restructure):
// s_nop 1, a0 tied to XP computed OUTSIDE the asm, plain fmac before the
// first DPP read of g. Same-chain fmacs 2 instrs apart >= fmac dep latency.
//
// g-trick: state g = 1/(2^s+1), h = 1-2g; rowsum(W_hh) folds into bias,
// -2*S2LE into weights; S2LE = 2*log2(e) pre-scales for exp2.
// Weights self-calibrated to the HW row_ror permutation (R1/R7-validated).
// Loads: R6 staged blocks, modulo-2 named buffers, no per-iter vmcnt drain.

#define S2LE 2.8853900817779268f  // 2*log2(e)

typedef float float4_ __attribute__((ext_vector_type(4)));

#define ROTI(v, N) __builtin_amdgcn_mov_dpp((v), 0x120 + (N), 0xF, 0xF, 0)
#define ROTF(v, N) __int_as_float(__builtin_amdgcn_mov_dpp(__float_as_int(v), 0x120 + (N), 0xF, 0xF, 0))

__global__ __launch_bounds__(64) void rnn_kernel(
    const float* __restrict__ x,
    const float* __restrict__ W_ih,
    const float* __restrict__ W_hh,
    const float* __restrict__ b_ih,
    const float* __restrict__ b_hh,
    const float* __restrict__ W_fc,
    const float* __restrict__ b_fc,
    float* __restrict__ out)
{
    const int li = (int)(threadIdx.x & 15u);
    const int b  = (int)((blockIdx.x * 64u + threadIdx.x) >> 4);

    const float* __restrict__ row = W_hh + li * 16;

    float sw = 0.0f;
#pragma unroll
    for (int j = 0; j < 16; ++j) sw += row[j];

    const float wsc = -2.0f * S2LE;

    // Self-calibrated weights: w[N] = wsc * W[li][sigma_N(li)], sigma_N =
    // the HW's row_ror:N permutation (validated end-to-end R1/R7).
    float w0  = wsc * row[li];
    float w1  = wsc * row[ROTI(li, 1)];
    float w2  = wsc * row[ROTI(li, 2)];
    float w3  = wsc * row[ROTI(li, 3)];
    float w4  = wsc * row[ROTI(li, 4)];
    float w5  = wsc * row[ROTI(li, 5)];
    float w6  = wsc * row[ROTI(li, 6)];
    float w7  = wsc * row[ROTI(li, 7)];
    float w8  = wsc * row[ROTI(li, 8)];
    float w9  = wsc * row[ROTI(li, 9)];
    float w10 = wsc * row[ROTI(li, 10)];
    float w11 = wsc * row[ROTI(li, 11)];
    float w12 = wsc * row[ROTI(li, 12)];
    float w13 = wsc * row[ROTI(li, 13)];
    float w14 = wsc * row[ROTI(li, 14)];
    float w15 = wsc * row[ROTI(li, 15)];

    const float wih  = W_ih[li] * S2LE;
    const float bias = (b_ih[li] + b_hh[li] + sw) * S2LE;
    const float wfc  = W_fc[li];
    const float bfc  = b_fc[0];

    const float4_* __restrict__ xv = (const float4_*)(x + (size_t)b * 512);

    float g = 0.5f;  // represents h = 0

    // One step: R7 head (s_nop 1, tied a0=XP, plain fmac first), then 2
    // interleaved DPP-fmac chains of depth 8; single tree add; exp2-
    // sigmoid tail (best measured: R5 poly +93, R8 newton +17 cyc/step).
#define STEP(XP) do { \
    float a0 = (XP), a1; \
    asm volatile( \
        "s_nop 1\n\t" \
        "v_fmac_f32 %0, %2, %3\n\t" \
        "v_mul_f32_dpp %1, %2, %11  row_ror:8  row_mask:0xf bank_mask:0xf\n\t" \
        "v_fmac_f32_dpp %0, %2, %4  row_ror:1  row_mask:0xf bank_mask:0xf\n\t" \
        "v_fmac_f32_dpp %1, %2, %12 row_ror:9  row_mask:0xf bank_mask:0xf\n\t" \
        "v_fmac_f32_dpp %0, %2, %5  row_ror:2  row_mask:0xf bank_mask:0xf\n\t" \
        "v_fmac_f32_dpp %1, %2, %13 row_ror:10 row_mask:0xf bank_mask:0xf\n\t" \
        "v_fmac_f32_dpp %0, %2, %6  row_ror:3  row_mask:0xf bank_mask:0xf\n\t" \
        "v_fmac_f32_dpp %1, %2, %14 row_ror:11 row_mask:0xf bank_mask:0xf\n\t" \
        "v_fmac_f32_dpp %0, %2, %7  row_ror:4  row_mask:0xf bank_mask:0xf\n\t" \
        "v_fmac_f32_dpp %1, %2, %15 row_ror:12 row_mask:0xf bank_mask:0xf\n\t" \
        "v_fmac_f32_dpp %0, %2, %8  row_ror:5  row_mask:0xf bank_mask:0xf\n\t" \
        "v_fmac_f32_dpp %1, %2, %16 row_ror:13 row_mask:0xf bank_mask:0xf\n\t" \
        "v_fmac_f32_dpp %0, %2, %9  row_ror:6  row_mask:0xf bank_mask:0xf\n\t" \
        "v_fmac_f32_dpp %1, %2, %17 row_ror:14 row_mask:0xf bank_mask:0xf\n\t" \
        "v_fmac_f32_dpp %0, %2, %10 row_ror:7  row_mask:0xf bank_mask:0xf\n\t" \
        "v_fmac_f32_dpp %1, %2, %18 row_ror:15 row_mask:0xf bank_mask:0xf\n\t" \
        : "+v"(a0), "=&v"(a1) \
        : "v"(g), \
          "v"(w0),  "v"(w1),  "v"(w2),  "v"(w3), \
          "v"(w4),  "v"(w5),  "v"(w6),  "v"(w7), \
          "v"(w8),  "v"(w9),  "v"(w10), "v"(w11), \
          "v"(w12), "v"(w13), "v"(w14), "v"(w15)); \
    float s_ = a0 + a1; \
    float e_ = __builtin_amdgcn_exp2f(s_); \
    g = __builtin_amdgcn_rcpf(e_ + 1.0f); \
} while (0)

// 16 recurrent steps from a 4-x-float4 staged block.
#define BLOCK(BUF) do { \
    _Pragma("unroll") \
    for (int j = 0; j < 4; ++j) { \
        STEP(fmaf((BUF)[j][0], wih, bias)); \
        STEP(fmaf((BUF)[j][1], wih, bias)); \
        STEP(fmaf((BUF)[j][2], wih, bias)); \
        STEP(fmaf((BUF)[j][3], wih, bias)); \
    } \
} while (0)

    float4_ bufA[4], bufB[4];
#pragma unroll
    for (int j = 0; j < 4; ++j) bufA[j] = xv[j];  // block 0

    // Unroll-2 modulo pipeline over 32 blocks of 16 timesteps (R6): loads
    // issue one full block ahead; no register rotation, no per-iter drain.
#pragma unroll 1
    for (int i = 0; i < 32; i += 2) {
#pragma unroll
        for (int j = 0; j < 4; ++j) bufB[j] = xv[(4 * (i + 1) + j) & 127];
        BLOCK(bufA);
#pragma unroll
        for (int j = 0; j < 4; ++j) bufA[j] = xv[(4 * (i + 2) + j) & 127];
        BLOCK(bufB);
    }
#undef BLOCK
#undef STEP

    // out[b] = sum_i wfc_i * h_i + bfc,  h = 1 - 2g (f32 g).
    float p = fmaf(-2.0f * wfc, g, wfc);
    p += ROTF(p, 8);
    p += ROTF(p, 4);
    p += ROTF(p, 2);
    p += ROTF(p, 1);
    if (li == 0) out[b] = p + bfc;
}

extern "C" void kernel_launch(void* const* d_in, const int* in_sizes, int n_in,
                              void* d_out, int out_size, void* d_ws, size_t ws_size,
                              hipStream_t stream) {
    const float* x    = (const float*)d_in[0];
    const float* W_ih = (const float*)d_in[1];
    const float* W_hh = (const float*)d_in[2];
    const float* b_ih = (const float*)d_in[3];
    const float* b_hh = (const float*)d_in[4];
    const float* W_fc = (const float*)d_in[5];
    const float* b_fc = (const float*)d_in[6];
    float* out = (float*)d_out;

    rnn_kernel<<<1024, 64, 0, stream>>>(x, W_ih, W_hh, b_ih, b_hh, W_fc, b_fc, out);
}